// Round 1
// baseline (590.785 us; speedup 1.0000x reference)
//
#include <hip/hip_runtime.h>

// SAGEConv (mean aggr, no bias): out = (segment_mean(x[src], dst)) @ W_l + x @ W_r
// x: [N,64] f32; edge_index: [2,E] int (harness converts int64->int32);
// W_l, W_r: [64,64] f32; out: [N,64] f32.

#define FDIM 64

// ---------------- Phase 1: edge scatter (one wave per edge) ----------------
__global__ __launch_bounds__(256) void sage_scatter(
    const float* __restrict__ x,
    const int* __restrict__ edge_index,  // [2, E] row-major: src row then dst row
    float* __restrict__ summed,          // [N, 64], pre-zeroed
    float* __restrict__ deg,             // [N], pre-zeroed
    int n_edges) {
  const int e = blockIdx.x * 4 + (threadIdx.x >> 6);
  const int lane = threadIdx.x & 63;
  if (e >= n_edges) return;
  const int src = edge_index[e];
  const int dst = edge_index[n_edges + e];
  const float v = x[src * FDIM + lane];
  unsafeAtomicAdd(&summed[dst * FDIM + lane], v);
  if (lane == 0) unsafeAtomicAdd(&deg[dst], 1.0f);
}

// ---------------- Phase 2: mean + dual GEMM epilogue (one wave per node) ----
__global__ __launch_bounds__(256) void sage_out(
    const float* __restrict__ x,
    const float* __restrict__ summed,
    const float* __restrict__ deg,
    const float* __restrict__ Wl,  // [64,64] row-major: Wl[k][f]
    const float* __restrict__ Wr,
    float* __restrict__ out,
    int n_nodes) {
  __shared__ float lWl[FDIM * FDIM];
  __shared__ float lWr[FDIM * FDIM];
  for (int i = threadIdx.x; i < FDIM * FDIM; i += 256) {
    lWl[i] = Wl[i];
    lWr[i] = Wr[i];
  }
  __syncthreads();

  const int node = blockIdx.x * 4 + (threadIdx.x >> 6);
  const int lane = threadIdx.x & 63;
  if (node >= n_nodes) return;

  const float d = deg[node];
  const float inv = 1.0f / fmaxf(d, 1.0f);
  const float m = summed[node * FDIM + lane] * inv;  // mean[node, lane]
  const float xr = x[node * FDIM + lane];            // x[node, lane]

  float acc = 0.0f;
#pragma unroll
  for (int k = 0; k < FDIM; ++k) {
    const float mk = __shfl(m, k, 64);
    const float xk = __shfl(xr, k, 64);
    acc += mk * lWl[k * FDIM + lane] + xk * lWr[k * FDIM + lane];
  }
  out[node * FDIM + lane] = acc;
}

extern "C" void kernel_launch(void* const* d_in, const int* in_sizes, int n_in,
                              void* d_out, int out_size, void* d_ws, size_t ws_size,
                              hipStream_t stream) {
  const float* x = (const float*)d_in[0];
  const int* edge_index = (const int*)d_in[1];
  const float* Wl = (const float*)d_in[2];
  const float* Wr = (const float*)d_in[3];
  float* out = (float*)d_out;

  const int n_nodes = in_sizes[0] / FDIM;      // 100000
  const int n_edges = in_sizes[1] / 2;         // 1200000

  float* summed = (float*)d_ws;                // [N, 64]
  float* deg = summed + (size_t)n_nodes * FDIM;  // [N]
  const size_t zero_bytes = (size_t)n_nodes * FDIM * sizeof(float) +
                            (size_t)n_nodes * sizeof(float);

  hipMemsetAsync(d_ws, 0, zero_bytes, stream);

  const int scatter_blocks = (n_edges + 3) / 4;
  sage_scatter<<<scatter_blocks, 256, 0, stream>>>(x, edge_index, summed, deg,
                                                   n_edges);

  const int out_blocks = (n_nodes + 3) / 4;
  sage_out<<<out_blocks, 256, 0, stream>>>(x, summed, deg, Wl, Wr, out, n_nodes);
}

// Round 2
// 437.059 us; speedup vs baseline: 1.3517x; 1.3517x over previous
//
#include <hip/hip_runtime.h>

// SAGEConv (mean aggr, no bias): out = segment_mean(x[src], dst) @ W_l + x @ W_r
// Strategy: counting-sort edges by dst (histogram -> scan -> bin), then a fused
// gather-sum + dual-GEMM-epilogue kernel. No fp32 atomics anywhere.

#define FDIM 64
#define SCAN_BS 1024

// ---- A: degree histogram (int atomics into 400 KB -> L2 resident) ----
__global__ __launch_bounds__(256) void k_hist(const int* __restrict__ dst,
                                              int* __restrict__ deg, int E) {
  int i = blockIdx.x * 256 + threadIdx.x;
  if (i < E) atomicAdd(&deg[dst[i]], 1);
}

// ---- B: per-block sums of deg ----
__global__ __launch_bounds__(SCAN_BS) void k_blocksum(const int* __restrict__ deg,
                                                      int* __restrict__ bsum, int N) {
  __shared__ int lds[SCAN_BS];
  int i = blockIdx.x * SCAN_BS + threadIdx.x;
  lds[threadIdx.x] = (i < N) ? deg[i] : 0;
  __syncthreads();
  for (int off = SCAN_BS / 2; off > 0; off >>= 1) {
    if (threadIdx.x < off) lds[threadIdx.x] += lds[threadIdx.x + off];
    __syncthreads();
  }
  if (threadIdx.x == 0) bsum[blockIdx.x] = lds[0];
}

// ---- C: exclusive scan of the (<=1024) block sums, single block ----
__global__ __launch_bounds__(SCAN_BS) void k_scanbsum(int* __restrict__ bsum, int NB) {
  __shared__ int lds[SCAN_BS];
  int t = threadIdx.x;
  lds[t] = (t < NB) ? bsum[t] : 0;
  __syncthreads();
  if (t == 0) {
    int run = 0;
    for (int i = 0; i < NB; ++i) { int v = lds[i]; lds[i] = run; run += v; }
  }
  __syncthreads();
  if (t < NB) bsum[t] = lds[t];
}

// ---- D: per-block exclusive scan + add block offset -> offsets, cursor ----
__global__ __launch_bounds__(SCAN_BS) void k_scan(const int* __restrict__ deg,
                                                  const int* __restrict__ bsum,
                                                  int* __restrict__ offsets,
                                                  int* __restrict__ cursor,
                                                  int N, int E) {
  __shared__ int lds[SCAN_BS];
  int i = blockIdx.x * SCAN_BS + threadIdx.x;
  int v = (i < N) ? deg[i] : 0;
  lds[threadIdx.x] = v;
  __syncthreads();
  for (int off = 1; off < SCAN_BS; off <<= 1) {
    int add = (threadIdx.x >= off) ? lds[threadIdx.x - off] : 0;
    __syncthreads();
    lds[threadIdx.x] += add;
    __syncthreads();
  }
  int excl = lds[threadIdx.x] - v + bsum[blockIdx.x];
  if (i < N) { offsets[i] = excl; cursor[i] = excl; }
  if (i == 0) offsets[N] = E;
}

// ---- E: bin edges into dst-sorted order ----
__global__ __launch_bounds__(256) void k_bin(const int* __restrict__ src,
                                             const int* __restrict__ dst,
                                             int* __restrict__ cursor,
                                             int* __restrict__ sorted_src, int E) {
  int i = blockIdx.x * 256 + threadIdx.x;
  if (i < E) {
    int d = dst[i];
    int pos = atomicAdd(&cursor[d], 1);
    sorted_src[pos] = src[i];
  }
}

// ---- F: fused gather-mean + dual GEMM epilogue (one wave per node) ----
__global__ __launch_bounds__(256) void k_agg(const float* __restrict__ x,
                                             const int* __restrict__ offsets,
                                             const int* __restrict__ sorted_src,
                                             const float* __restrict__ Wl,
                                             const float* __restrict__ Wr,
                                             float* __restrict__ out, int n_nodes) {
  __shared__ float lWl[FDIM * FDIM];
  __shared__ float lWr[FDIM * FDIM];
  for (int i = threadIdx.x; i < FDIM * FDIM; i += 256) {
    lWl[i] = Wl[i];
    lWr[i] = Wr[i];
  }
  __syncthreads();

  const int node = blockIdx.x * 4 + (threadIdx.x >> 6);
  const int lane = threadIdx.x & 63;
  if (node >= n_nodes) return;

  const int start = offsets[node];
  const int end = offsets[node + 1];
  const int degree = end - start;

  float s = 0.0f;
  int i = start;
  for (; i + 4 <= end; i += 4) {
    const int s0 = sorted_src[i], s1 = sorted_src[i + 1];
    const int s2 = sorted_src[i + 2], s3 = sorted_src[i + 3];
    const float v0 = x[s0 * FDIM + lane];
    const float v1 = x[s1 * FDIM + lane];
    const float v2 = x[s2 * FDIM + lane];
    const float v3 = x[s3 * FDIM + lane];
    s += v0 + v1 + v2 + v3;
  }
  for (; i < end; ++i) s += x[sorted_src[i] * FDIM + lane];

  const float inv = 1.0f / (float)max(degree, 1);
  const float m = s * inv;                 // mean[node, lane]
  const float xr = x[node * FDIM + lane];  // x[node, lane]

  float acc = 0.0f;
#pragma unroll
  for (int k = 0; k < FDIM; ++k) {
    const float mk = __shfl(m, k, 64);
    const float xk = __shfl(xr, k, 64);
    acc += mk * lWl[k * FDIM + lane] + xk * lWr[k * FDIM + lane];
  }
  out[node * FDIM + lane] = acc;
}

extern "C" void kernel_launch(void* const* d_in, const int* in_sizes, int n_in,
                              void* d_out, int out_size, void* d_ws, size_t ws_size,
                              hipStream_t stream) {
  const float* x = (const float*)d_in[0];
  const int* edge_index = (const int*)d_in[1];
  const float* Wl = (const float*)d_in[2];
  const float* Wr = (const float*)d_in[3];
  float* out = (float*)d_out;

  const int n_nodes = in_sizes[0] / FDIM;  // 100000
  const int n_edges = in_sizes[1] / 2;     // 1200000
  const int* e_src = edge_index;
  const int* e_dst = edge_index + n_edges;

  const int NB = (n_nodes + SCAN_BS - 1) / SCAN_BS;  // 98

  // ws layout (ints)
  int* deg = (int*)d_ws;                 // N
  int* bsum = deg + n_nodes;             // NB (pad 1024)
  int* offsets = bsum + SCAN_BS;         // N+1
  int* cursor = offsets + n_nodes + 1;   // N
  int* sorted_src = cursor + n_nodes;    // E

  hipMemsetAsync(deg, 0, (size_t)n_nodes * sizeof(int), stream);

  k_hist<<<(n_edges + 255) / 256, 256, 0, stream>>>(e_dst, deg, n_edges);
  k_blocksum<<<NB, SCAN_BS, 0, stream>>>(deg, bsum, n_nodes);
  k_scanbsum<<<1, SCAN_BS, 0, stream>>>(bsum, NB);
  k_scan<<<NB, SCAN_BS, 0, stream>>>(deg, bsum, offsets, cursor, n_nodes, n_edges);
  k_bin<<<(n_edges + 255) / 256, 256, 0, stream>>>(e_src, e_dst, cursor, sorted_src,
                                                   n_edges);
  k_agg<<<(n_nodes + 3) / 4, 256, 0, stream>>>(x, offsets, sorted_src, Wl, Wr, out,
                                               n_nodes);
}

// Round 3
// 424.448 us; speedup vs baseline: 1.3919x; 1.0297x over previous
//
#include <hip/hip_runtime.h>

// SAGEConv (mean aggr, no bias): out = segment_mean(x[src], dst) @ W_l + x @ W_r
// Counting-sort edges by dst (histogram -> scan -> bin), then a fused
// float4-gather-sum + dual-GEMM-epilogue kernel. No fp32 atomics.

#define FDIM 64
#define SCAN_BS 1024

// ---- A: degree histogram ----
__global__ __launch_bounds__(256) void k_hist(const int* __restrict__ dst,
                                              int* __restrict__ deg, int E) {
  int i = blockIdx.x * 256 + threadIdx.x;
  if (i < E) atomicAdd(&deg[dst[i]], 1);
}

// ---- B: per-block sums of deg ----
__global__ __launch_bounds__(SCAN_BS) void k_blocksum(const int* __restrict__ deg,
                                                      int* __restrict__ bsum, int N) {
  __shared__ int lds[SCAN_BS];
  int i = blockIdx.x * SCAN_BS + threadIdx.x;
  lds[threadIdx.x] = (i < N) ? deg[i] : 0;
  __syncthreads();
  for (int off = SCAN_BS / 2; off > 0; off >>= 1) {
    if (threadIdx.x < off) lds[threadIdx.x] += lds[threadIdx.x + off];
    __syncthreads();
  }
  if (threadIdx.x == 0) bsum[blockIdx.x] = lds[0];
}

// ---- C: exclusive scan of the (<=1024) block sums ----
__global__ __launch_bounds__(SCAN_BS) void k_scanbsum(int* __restrict__ bsum, int NB) {
  __shared__ int lds[SCAN_BS];
  int t = threadIdx.x;
  lds[t] = (t < NB) ? bsum[t] : 0;
  __syncthreads();
  if (t == 0) {
    int run = 0;
    for (int i = 0; i < NB; ++i) { int v = lds[i]; lds[i] = run; run += v; }
  }
  __syncthreads();
  if (t < NB) bsum[t] = lds[t];
}

// ---- D: per-block exclusive scan + block offset -> offsets, cursor ----
__global__ __launch_bounds__(SCAN_BS) void k_scan(const int* __restrict__ deg,
                                                  const int* __restrict__ bsum,
                                                  int* __restrict__ offsets,
                                                  int* __restrict__ cursor,
                                                  int N, int E) {
  __shared__ int lds[SCAN_BS];
  int i = blockIdx.x * SCAN_BS + threadIdx.x;
  int v = (i < N) ? deg[i] : 0;
  lds[threadIdx.x] = v;
  __syncthreads();
  for (int off = 1; off < SCAN_BS; off <<= 1) {
    int add = (threadIdx.x >= off) ? lds[threadIdx.x - off] : 0;
    __syncthreads();
    lds[threadIdx.x] += add;
    __syncthreads();
  }
  int excl = lds[threadIdx.x] - v + bsum[blockIdx.x];
  if (i < N) { offsets[i] = excl; cursor[i] = excl; }
  if (i == 0) offsets[N] = E;
}

// ---- E: bin edges into dst-sorted order ----
__global__ __launch_bounds__(256) void k_bin(const int* __restrict__ src,
                                             const int* __restrict__ dst,
                                             int* __restrict__ cursor,
                                             int* __restrict__ sorted_src, int E) {
  int i = blockIdx.x * 256 + threadIdx.x;
  if (i < E) {
    int d = dst[i];
    int pos = atomicAdd(&cursor[d], 1);
    sorted_src[pos] = src[i];
  }
}

// ---- F: fused float4-gather-mean + dual GEMM epilogue (wave per node) ----
// Lane layout: c = lane & 15 (feature quad, 16 B), g = lane >> 4 (edge slot).
// One wave-wide float4 load gathers 4 full 256 B rows -> 1 KB per instruction.
__global__ __launch_bounds__(256) void k_agg(const float* __restrict__ x,
                                             const int* __restrict__ offsets,
                                             const int* __restrict__ sorted_src,
                                             const float* __restrict__ Wl,
                                             const float* __restrict__ Wr,
                                             float* __restrict__ out, int n_nodes) {
  __shared__ float lWl[FDIM * FDIM];
  __shared__ float lWr[FDIM * FDIM];
  for (int i = threadIdx.x; i < FDIM * FDIM; i += 256) {
    lWl[i] = Wl[i];
    lWr[i] = Wr[i];
  }
  __syncthreads();

  const int node = blockIdx.x * 4 + (threadIdx.x >> 6);
  const int lane = threadIdx.x & 63;
  if (node >= n_nodes) return;

  const int c = lane & 15;   // feature quad
  const int g = lane >> 4;   // edge subgroup 0..3

  const int start = offsets[node];
  const int end = offsets[node + 1];
  const int degree = end - start;

  float4 s = make_float4(0.f, 0.f, 0.f, 0.f);

  for (int base = start; base < end; base += 64) {
    const int e = base + lane;
    const int idx = (e < end) ? sorted_src[e] : node;  // pad = safe address
    const int nIn = min(end - base, 64);
    const int G = (nIn + 3) >> 2;
#pragma unroll 4
    for (int j = 0; j < G; ++j) {
      const int sub = 4 * j + g;
      const int se = __shfl(idx, sub, 64);
      const float wm = (sub < nIn) ? 1.0f : 0.0f;
      const float4 v = *(const float4*)(x + (size_t)se * FDIM + (c << 2));
      s.x = fmaf(v.x, wm, s.x);
      s.y = fmaf(v.y, wm, s.y);
      s.z = fmaf(v.z, wm, s.z);
      s.w = fmaf(v.w, wm, s.w);
    }
  }

  // reduce across the 4 edge subgroups (lanes c, c+16, c+32, c+48)
  s.x += __shfl_xor(s.x, 16, 64);
  s.y += __shfl_xor(s.y, 16, 64);
  s.z += __shfl_xor(s.z, 16, 64);
  s.w += __shfl_xor(s.w, 16, 64);
  s.x += __shfl_xor(s.x, 32, 64);
  s.y += __shfl_xor(s.y, 32, 64);
  s.z += __shfl_xor(s.z, 32, 64);
  s.w += __shfl_xor(s.w, 32, 64);

  const float inv = 1.0f / (float)max(degree, 1);
  const float m4[4] = {s.x * inv, s.y * inv, s.z * inv, s.w * inv};

  const float4 xr4 = *(const float4*)(x + (size_t)node * FDIM + (c << 2));
  const float x4[4] = {xr4.x, xr4.y, xr4.z, xr4.w};

  float acc = 0.0f;
#pragma unroll
  for (int f = 0; f < FDIM; ++f) {
    const float mk = __shfl(m4[f & 3], f >> 2, 64);
    const float xk = __shfl(x4[f & 3], f >> 2, 64);
    acc = fmaf(mk, lWl[f * FDIM + lane], acc);
    acc = fmaf(xk, lWr[f * FDIM + lane], acc);
  }
  out[node * FDIM + lane] = acc;
}

extern "C" void kernel_launch(void* const* d_in, const int* in_sizes, int n_in,
                              void* d_out, int out_size, void* d_ws, size_t ws_size,
                              hipStream_t stream) {
  const float* x = (const float*)d_in[0];
  const int* edge_index = (const int*)d_in[1];
  const float* Wl = (const float*)d_in[2];
  const float* Wr = (const float*)d_in[3];
  float* out = (float*)d_out;

  const int n_nodes = in_sizes[0] / FDIM;  // 100000
  const int n_edges = in_sizes[1] / 2;     // 1200000
  const int* e_src = edge_index;
  const int* e_dst = edge_index + n_edges;

  const int NB = (n_nodes + SCAN_BS - 1) / SCAN_BS;  // 98

  // ws layout (ints)
  int* deg = (int*)d_ws;                // N
  int* bsum = deg + n_nodes;            // pad SCAN_BS
  int* offsets = bsum + SCAN_BS;        // N+1
  int* cursor = offsets + n_nodes + 1;  // N
  int* sorted_src = cursor + n_nodes;   // E

  hipMemsetAsync(deg, 0, (size_t)n_nodes * sizeof(int), stream);

  k_hist<<<(n_edges + 255) / 256, 256, 0, stream>>>(e_dst, deg, n_edges);
  k_blocksum<<<NB, SCAN_BS, 0, stream>>>(deg, bsum, n_nodes);
  k_scanbsum<<<1, SCAN_BS, 0, stream>>>(bsum, NB);
  k_scan<<<NB, SCAN_BS, 0, stream>>>(deg, bsum, offsets, cursor, n_nodes, n_edges);
  k_bin<<<(n_edges + 255) / 256, 256, 0, stream>>>(e_src, e_dst, cursor, sorted_src,
                                                   n_edges);
  k_agg<<<(n_nodes + 3) / 4, 256, 0, stream>>>(x, offsets, sorted_src, Wl, Wr, out,
                                               n_nodes);
}

// Round 4
// 318.873 us; speedup vs baseline: 1.8527x; 1.3311x over previous
//
#include <hip/hip_runtime.h>

// SAGEConv (mean aggr, no bias): out = segment_mean(x[src], dst) @ W_l + x @ W_r
// Counting-sort edges by dst -> gather-mean (wave/node, float4) -> tiled
// register-blocked GEMM: out = [mean | x] @ [Wl; Wr]. mean lives in d_out
// (in-place safe: each GEMM block loads its rows to LDS before overwriting).

#define FDIM 64
#define SCAN_BS 1024

// ---- A: degree histogram ----
__global__ __launch_bounds__(256) void k_hist(const int* __restrict__ dst,
                                              int* __restrict__ deg, int E) {
  int i = blockIdx.x * 256 + threadIdx.x;
  if (i < E) atomicAdd(&deg[dst[i]], 1);
}

// ---- B: per-block sums of deg ----
__global__ __launch_bounds__(SCAN_BS) void k_blocksum(const int* __restrict__ deg,
                                                      int* __restrict__ bsum, int N) {
  __shared__ int lds[SCAN_BS];
  int i = blockIdx.x * SCAN_BS + threadIdx.x;
  lds[threadIdx.x] = (i < N) ? deg[i] : 0;
  __syncthreads();
  for (int off = SCAN_BS / 2; off > 0; off >>= 1) {
    if (threadIdx.x < off) lds[threadIdx.x] += lds[threadIdx.x + off];
    __syncthreads();
  }
  if (threadIdx.x == 0) bsum[blockIdx.x] = lds[0];
}

// ---- C: exclusive scan of the (<=1024) block sums ----
__global__ __launch_bounds__(SCAN_BS) void k_scanbsum(int* __restrict__ bsum, int NB) {
  __shared__ int lds[SCAN_BS];
  int t = threadIdx.x;
  lds[t] = (t < NB) ? bsum[t] : 0;
  __syncthreads();
  if (t == 0) {
    int run = 0;
    for (int i = 0; i < NB; ++i) { int v = lds[i]; lds[i] = run; run += v; }
  }
  __syncthreads();
  if (t < NB) bsum[t] = lds[t];
}

// ---- D: per-block exclusive scan + block offset -> offsets, cursor ----
__global__ __launch_bounds__(SCAN_BS) void k_scan(const int* __restrict__ deg,
                                                  const int* __restrict__ bsum,
                                                  int* __restrict__ offsets,
                                                  int* __restrict__ cursor,
                                                  int N, int E) {
  __shared__ int lds[SCAN_BS];
  int i = blockIdx.x * SCAN_BS + threadIdx.x;
  int v = (i < N) ? deg[i] : 0;
  lds[threadIdx.x] = v;
  __syncthreads();
  for (int off = 1; off < SCAN_BS; off <<= 1) {
    int add = (threadIdx.x >= off) ? lds[threadIdx.x - off] : 0;
    __syncthreads();
    lds[threadIdx.x] += add;
    __syncthreads();
  }
  int excl = lds[threadIdx.x] - v + bsum[blockIdx.x];
  if (i < N) { offsets[i] = excl; cursor[i] = excl; }
  if (i == 0) offsets[N] = E;
}

// ---- E: bin edges into dst-sorted order ----
__global__ __launch_bounds__(256) void k_bin(const int* __restrict__ src,
                                             const int* __restrict__ dst,
                                             int* __restrict__ cursor,
                                             int* __restrict__ sorted_src, int E) {
  int i = blockIdx.x * 256 + threadIdx.x;
  if (i < E) {
    int d = dst[i];
    int pos = atomicAdd(&cursor[d], 1);
    sorted_src[pos] = src[i];
  }
}

// ---- F: gather-mean only (wave per node, float4 lanes) -> mean in d_out ----
// Lane layout: c = lane & 15 (feature quad), g = lane >> 4 (edge slot 0..3).
__global__ __launch_bounds__(256) void k_agg(const float* __restrict__ x,
                                             const int* __restrict__ offsets,
                                             const int* __restrict__ sorted_src,
                                             float* __restrict__ mean, int n_nodes) {
  const int node = blockIdx.x * 4 + (threadIdx.x >> 6);
  const int lane = threadIdx.x & 63;
  if (node >= n_nodes) return;

  const int c = lane & 15;
  const int g = lane >> 4;

  const int start = offsets[node];
  const int end = offsets[node + 1];
  const int degree = end - start;

  float4 s = make_float4(0.f, 0.f, 0.f, 0.f);

  for (int base = start; base < end; base += 64) {
    const int e = base + lane;
    const int idx = (e < end) ? sorted_src[e] : node;  // pad = safe address
    const int nIn = min(end - base, 64);
    const int G = (nIn + 3) >> 2;
#pragma unroll 4
    for (int j = 0; j < G; ++j) {
      const int sub = 4 * j + g;
      const int se = __shfl(idx, sub, 64);
      const float wm = (sub < nIn) ? 1.0f : 0.0f;
      const float4 v = *(const float4*)(x + (size_t)se * FDIM + (c << 2));
      s.x = fmaf(v.x, wm, s.x);
      s.y = fmaf(v.y, wm, s.y);
      s.z = fmaf(v.z, wm, s.z);
      s.w = fmaf(v.w, wm, s.w);
    }
  }

  s.x += __shfl_xor(s.x, 16, 64);
  s.y += __shfl_xor(s.y, 16, 64);
  s.z += __shfl_xor(s.z, 16, 64);
  s.w += __shfl_xor(s.w, 16, 64);
  s.x += __shfl_xor(s.x, 32, 64);
  s.y += __shfl_xor(s.y, 32, 64);
  s.z += __shfl_xor(s.z, 32, 64);
  s.w += __shfl_xor(s.w, 32, 64);

  if (g == 0) {
    const float inv = 1.0f / (float)max(degree, 1);
    *(float4*)(mean + (size_t)node * FDIM + (c << 2)) =
        make_float4(s.x * inv, s.y * inv, s.z * inv, s.w * inv);
  }
}

// ---- G: tiled GEMM  out = [mean | x] @ [Wl ; Wr], in-place on mean ----
// 64 nodes/block, K=128. Each thread: 4 nodes x 4 feats register block.
__global__ __launch_bounds__(256) void k_gemm(const float* __restrict__ x,
                                              const float* __restrict__ Wl,
                                              const float* __restrict__ Wr,
                                              float* __restrict__ outmean,
                                              int n_nodes) {
  __shared__ float At[64 * 128];  // [node][k]  k<64: mean, k>=64: x
  __shared__ float Wt[128 * 64];  // [k][f]     k<64: Wl,   k>=64: Wr

  const int t = threadIdx.x;
  const int nodebase = blockIdx.x * 64;

  // W tiles: straight 16 KB copies each
  {
    const float4* wl4 = (const float4*)Wl;
    const float4* wr4 = (const float4*)Wr;
    float4* wt4 = (float4*)Wt;
#pragma unroll
    for (int i = 0; i < 4; ++i) {
      wt4[i * 256 + t] = wl4[i * 256 + t];
      wt4[1024 + i * 256 + t] = wr4[i * 256 + t];
    }
  }
  // A tile: interleave mean row (k 0..63) and x row (k 64..127)
#pragma unroll
  for (int it = 0; it < 4; ++it) {
    const int idx = it * 256 + t;  // 0..1023
    const int row = idx >> 4;
    const int q = idx & 15;
    const int node = min(nodebase + row, n_nodes - 1);
    const float4 mv = *(const float4*)(outmean + (size_t)node * FDIM + q * 4);
    const float4 xv = *(const float4*)(x + (size_t)node * FDIM + q * 4);
    *(float4*)(At + row * 128 + q * 4) = mv;
    *(float4*)(At + row * 128 + 64 + q * 4) = xv;
  }
  __syncthreads();

  const int fbase = (t & 15) * 4;
  const int nb = (t >> 4) * 4;

  float acc[4][4];
#pragma unroll
  for (int i = 0; i < 4; ++i)
#pragma unroll
    for (int j = 0; j < 4; ++j) acc[i][j] = 0.0f;

#pragma unroll 8
  for (int k4 = 0; k4 < 32; ++k4) {
    const int k = k4 * 4;
    float4 a[4], w[4];
#pragma unroll
    for (int i = 0; i < 4; ++i)
      a[i] = *(const float4*)(At + (nb + i) * 128 + k);
#pragma unroll
    for (int kk = 0; kk < 4; ++kk)
      w[kk] = *(const float4*)(Wt + (k + kk) * 64 + fbase);
#pragma unroll
    for (int i = 0; i < 4; ++i) {
      acc[i][0] = fmaf(a[i].x, w[0].x, acc[i][0]);
      acc[i][1] = fmaf(a[i].x, w[0].y, acc[i][1]);
      acc[i][2] = fmaf(a[i].x, w[0].z, acc[i][2]);
      acc[i][3] = fmaf(a[i].x, w[0].w, acc[i][3]);
      acc[i][0] = fmaf(a[i].y, w[1].x, acc[i][0]);
      acc[i][1] = fmaf(a[i].y, w[1].y, acc[i][1]);
      acc[i][2] = fmaf(a[i].y, w[1].z, acc[i][2]);
      acc[i][3] = fmaf(a[i].y, w[1].w, acc[i][3]);
      acc[i][0] = fmaf(a[i].z, w[2].x, acc[i][0]);
      acc[i][1] = fmaf(a[i].z, w[2].y, acc[i][1]);
      acc[i][2] = fmaf(a[i].z, w[2].z, acc[i][2]);
      acc[i][3] = fmaf(a[i].z, w[2].w, acc[i][3]);
      acc[i][0] = fmaf(a[i].w, w[3].x, acc[i][0]);
      acc[i][1] = fmaf(a[i].w, w[3].y, acc[i][1]);
      acc[i][2] = fmaf(a[i].w, w[3].z, acc[i][2]);
      acc[i][3] = fmaf(a[i].w, w[3].w, acc[i][3]);
    }
  }

#pragma unroll
  for (int i = 0; i < 4; ++i) {
    const int node = nodebase + nb + i;
    if (node < n_nodes)
      *(float4*)(outmean + (size_t)node * FDIM + fbase) =
          make_float4(acc[i][0], acc[i][1], acc[i][2], acc[i][3]);
  }
}

extern "C" void kernel_launch(void* const* d_in, const int* in_sizes, int n_in,
                              void* d_out, int out_size, void* d_ws, size_t ws_size,
                              hipStream_t stream) {
  const float* x = (const float*)d_in[0];
  const int* edge_index = (const int*)d_in[1];
  const float* Wl = (const float*)d_in[2];
  const float* Wr = (const float*)d_in[3];
  float* out = (float*)d_out;

  const int n_nodes = in_sizes[0] / FDIM;  // 100000
  const int n_edges = in_sizes[1] / 2;     // 1200000
  const int* e_src = edge_index;
  const int* e_dst = edge_index + n_edges;

  const int NB = (n_nodes + SCAN_BS - 1) / SCAN_BS;  // 98

  // ws layout (ints)
  int* deg = (int*)d_ws;                // N
  int* bsum = deg + n_nodes;            // pad SCAN_BS
  int* offsets = bsum + SCAN_BS;        // N+1
  int* cursor = offsets + n_nodes + 1;  // N
  int* sorted_src = cursor + n_nodes;   // E

  hipMemsetAsync(deg, 0, (size_t)n_nodes * sizeof(int), stream);

  k_hist<<<(n_edges + 255) / 256, 256, 0, stream>>>(e_dst, deg, n_edges);
  k_blocksum<<<NB, SCAN_BS, 0, stream>>>(deg, bsum, n_nodes);
  k_scanbsum<<<1, SCAN_BS, 0, stream>>>(bsum, NB);
  k_scan<<<NB, SCAN_BS, 0, stream>>>(deg, bsum, offsets, cursor, n_nodes, n_edges);
  k_bin<<<(n_edges + 255) / 256, 256, 0, stream>>>(e_src, e_dst, cursor, sorted_src,
                                                   n_edges);
  k_agg<<<(n_nodes + 3) / 4, 256, 0, stream>>>(x, offsets, sorted_src, out, n_nodes);
  k_gemm<<<(n_nodes + 63) / 64, 256, 0, stream>>>(x, Wl, Wr, out, n_nodes);
}

// Round 5
// 277.758 us; speedup vs baseline: 2.1270x; 1.1480x over previous
//
#include <hip/hip_runtime.h>
#include <stdint.h>

// SAGEConv (mean aggr, no bias): out = segment_mean(x[src], dst) @ W_l + x @ W_r
// Pipeline: node-degree hist -> scan -> two-level partition (bucket by dst>>10,
// then L2-local sub-scatter) -> gather-mean (wave/node, float4) -> tiled GEMM
// out = [mean | x] @ [Wl; Wr] (mean staged in d_out, overwritten in place).

#define FDIM 64
#define SCAN_BS 1024
#define NPB 1024      // nodes per bucket (dst >> 10)
#define PART_T 2048   // edges per partition block
#define MAXBKT 128    // >= ceil(100000/1024) = 98

// ---- A: degree histogram ----
__global__ __launch_bounds__(256) void k_hist(const int* __restrict__ dst,
                                              int* __restrict__ deg, int E) {
  int i = blockIdx.x * 256 + threadIdx.x;
  if (i < E) atomicAdd(&deg[dst[i]], 1);
}

// ---- B: per-block sums of deg ----
__global__ __launch_bounds__(SCAN_BS) void k_blocksum(const int* __restrict__ deg,
                                                      int* __restrict__ bsum, int N) {
  __shared__ int lds[SCAN_BS];
  int i = blockIdx.x * SCAN_BS + threadIdx.x;
  lds[threadIdx.x] = (i < N) ? deg[i] : 0;
  __syncthreads();
  for (int off = SCAN_BS / 2; off > 0; off >>= 1) {
    if (threadIdx.x < off) lds[threadIdx.x] += lds[threadIdx.x + off];
    __syncthreads();
  }
  if (threadIdx.x == 0) bsum[blockIdx.x] = lds[0];
}

// ---- C: exclusive scan of the (<=1024) block sums ----
__global__ __launch_bounds__(SCAN_BS) void k_scanbsum(int* __restrict__ bsum, int NB) {
  __shared__ int lds[SCAN_BS];
  int t = threadIdx.x;
  lds[t] = (t < NB) ? bsum[t] : 0;
  __syncthreads();
  if (t == 0) {
    int run = 0;
    for (int i = 0; i < NB; ++i) { int v = lds[i]; lds[i] = run; run += v; }
  }
  __syncthreads();
  if (t < NB) bsum[t] = lds[t];
}

// ---- D: per-block exclusive scan + block offset -> offsets ----
__global__ __launch_bounds__(SCAN_BS) void k_scan(const int* __restrict__ deg,
                                                  const int* __restrict__ bsum,
                                                  int* __restrict__ offsets,
                                                  int N, int E) {
  __shared__ int lds[SCAN_BS];
  int i = blockIdx.x * SCAN_BS + threadIdx.x;
  int v = (i < N) ? deg[i] : 0;
  lds[threadIdx.x] = v;
  __syncthreads();
  for (int off = 1; off < SCAN_BS; off <<= 1) {
    int add = (threadIdx.x >= off) ? lds[threadIdx.x - off] : 0;
    __syncthreads();
    lds[threadIdx.x] += add;
    __syncthreads();
  }
  int excl = lds[threadIdx.x] - v + bsum[blockIdx.x];
  if (i < N) offsets[i] = excl;
  if (i == 0) offsets[N] = E;
}

// ---- D2: init per-bucket global cursors from offsets ----
__global__ void k_initB(const int* __restrict__ offsets, int* __restrict__ cursorB,
                        int nbkt, int n_nodes) {
  int t = threadIdx.x;
  if (t < nbkt) cursorB[t] = offsets[min(t * NPB, n_nodes)];
}

// ---- E1: partition edges into dst-buckets (coalesced run writes) ----
__global__ __launch_bounds__(256) void k_part(const int* __restrict__ esrc,
                                              const int* __restrict__ edst,
                                              int* __restrict__ cursorB,
                                              int2* __restrict__ pairs, int E) {
  __shared__ int cnt[MAXBKT], excl0[MAXBKT], cursorL[MAXBKT], gbase[MAXBKT];
  __shared__ int sc[MAXBKT];
  __shared__ int2 buf[PART_T];
  const int t = threadIdx.x;
  const int base = blockIdx.x * PART_T;
  const int nvalid = min(E - base, PART_T);

  for (int b = t; b < MAXBKT; b += 256) cnt[b] = 0;
  __syncthreads();

  int s[8], d[8], bk[8];
#pragma unroll
  for (int i = 0; i < 8; ++i) {
    const int e = base + i * 256 + t;
    if (e < E) {
      s[i] = esrc[e];
      d[i] = edst[e];
      bk[i] = d[i] >> 10;
      atomicAdd(&cnt[bk[i]], 1);
    } else {
      bk[i] = -1;
    }
  }
  __syncthreads();

  // exclusive scan of cnt over MAXBKT via Hillis-Steele
  if (t < MAXBKT) sc[t] = cnt[t];
  __syncthreads();
  for (int off = 1; off < MAXBKT; off <<= 1) {
    int v = 0;
    if (t < MAXBKT && t >= off) v = sc[t - off];
    __syncthreads();
    if (t < MAXBKT) sc[t] += v;
    __syncthreads();
  }
  if (t < MAXBKT) {
    excl0[t] = sc[t] - cnt[t];
    cursorL[t] = excl0[t];
  }
  __syncthreads();

  // reorder into LDS grouped by bucket
#pragma unroll
  for (int i = 0; i < 8; ++i) {
    if (bk[i] >= 0) {
      int slot = atomicAdd(&cursorL[bk[i]], 1);
      buf[slot] = make_int2(s[i], d[i]);
    }
  }
  __syncthreads();

  // reserve global space per bucket
  if (t < MAXBKT && cnt[t] > 0) gbase[t] = atomicAdd(&cursorB[t], cnt[t]);
  __syncthreads();

  // write runs out (consecutive idx -> consecutive global pos per bucket)
  for (int idx = t; idx < nvalid; idx += 256) {
    int2 p = buf[idx];
    int b = p.y >> 10;
    pairs[gbase[b] + (idx - excl0[b])] = p;
  }
}

// ---- E2: within-bucket scatter to final CSR order (L2-local writes) ----
__global__ __launch_bounds__(256) void k_sub(const int2* __restrict__ pairs,
                                             const int* __restrict__ offsets,
                                             int* __restrict__ sorted_src,
                                             int n_nodes) {
  __shared__ int cur[NPB];
  const int nodebase = blockIdx.x * NPB;
  const int nodeend = min(nodebase + NPB, n_nodes);
  for (int i = threadIdx.x; i < NPB; i += 256) cur[i] = 0;
  __syncthreads();
  const int rstart = offsets[nodebase];
  const int rend = offsets[nodeend];
  for (int i = rstart + threadIdx.x; i < rend; i += 256) {
    int2 p = pairs[i];
    int r = atomicAdd(&cur[p.y - nodebase], 1);
    sorted_src[offsets[p.y] + r] = p.x;
  }
}

// ---- F: gather-mean (wave per node, float4 lanes) -> mean in d_out ----
__global__ __launch_bounds__(256) void k_agg(const float* __restrict__ x,
                                             const int* __restrict__ offsets,
                                             const int* __restrict__ sorted_src,
                                             float* __restrict__ mean, int n_nodes) {
  const int node = blockIdx.x * 4 + (threadIdx.x >> 6);
  const int lane = threadIdx.x & 63;
  if (node >= n_nodes) return;

  const int c = lane & 15;
  const int g = lane >> 4;

  const int start = offsets[node];
  const int end = offsets[node + 1];
  const int degree = end - start;

  float4 s = make_float4(0.f, 0.f, 0.f, 0.f);

  for (int base = start; base < end; base += 64) {
    const int e = base + lane;
    const int idx = (e < end) ? sorted_src[e] : node;  // pad = safe address
    const int nIn = min(end - base, 64);
    const int G = (nIn + 3) >> 2;
#pragma unroll 4
    for (int j = 0; j < G; ++j) {
      const int sub = 4 * j + g;
      const int se = __shfl(idx, sub, 64);
      const float wm = (sub < nIn) ? 1.0f : 0.0f;
      const float4 v = *(const float4*)(x + (size_t)se * FDIM + (c << 2));
      s.x = fmaf(v.x, wm, s.x);
      s.y = fmaf(v.y, wm, s.y);
      s.z = fmaf(v.z, wm, s.z);
      s.w = fmaf(v.w, wm, s.w);
    }
  }

  s.x += __shfl_xor(s.x, 16, 64);
  s.y += __shfl_xor(s.y, 16, 64);
  s.z += __shfl_xor(s.z, 16, 64);
  s.w += __shfl_xor(s.w, 16, 64);
  s.x += __shfl_xor(s.x, 32, 64);
  s.y += __shfl_xor(s.y, 32, 64);
  s.z += __shfl_xor(s.z, 32, 64);
  s.w += __shfl_xor(s.w, 32, 64);

  if (g == 0) {
    const float inv = 1.0f / (float)max(degree, 1);
    *(float4*)(mean + (size_t)node * FDIM + (c << 2)) =
        make_float4(s.x * inv, s.y * inv, s.z * inv, s.w * inv);
  }
}

// ---- G: tiled GEMM  out = [mean | x] @ [Wl ; Wr], in-place on mean ----
__global__ __launch_bounds__(256) void k_gemm(const float* __restrict__ x,
                                              const float* __restrict__ Wl,
                                              const float* __restrict__ Wr,
                                              float* __restrict__ outmean,
                                              int n_nodes) {
  __shared__ float At[64 * 128];  // [node][k]  k<64: mean, k>=64: x
  __shared__ float Wt[128 * 64];  // [k][f]     k<64: Wl,   k>=64: Wr

  const int t = threadIdx.x;
  const int nodebase = blockIdx.x * 64;

  {
    const float4* wl4 = (const float4*)Wl;
    const float4* wr4 = (const float4*)Wr;
    float4* wt4 = (float4*)Wt;
#pragma unroll
    for (int i = 0; i < 4; ++i) {
      wt4[i * 256 + t] = wl4[i * 256 + t];
      wt4[1024 + i * 256 + t] = wr4[i * 256 + t];
    }
  }
#pragma unroll
  for (int it = 0; it < 4; ++it) {
    const int idx = it * 256 + t;  // 0..1023
    const int row = idx >> 4;
    const int q = idx & 15;
    const int node = min(nodebase + row, n_nodes - 1);
    const float4 mv = *(const float4*)(outmean + (size_t)node * FDIM + q * 4);
    const float4 xv = *(const float4*)(x + (size_t)node * FDIM + q * 4);
    *(float4*)(At + row * 128 + q * 4) = mv;
    *(float4*)(At + row * 128 + 64 + q * 4) = xv;
  }
  __syncthreads();

  const int fbase = (t & 15) * 4;
  const int nb = (t >> 4) * 4;

  float acc[4][4];
#pragma unroll
  for (int i = 0; i < 4; ++i)
#pragma unroll
    for (int j = 0; j < 4; ++j) acc[i][j] = 0.0f;

#pragma unroll 8
  for (int k4 = 0; k4 < 32; ++k4) {
    const int k = k4 * 4;
    float4 a[4], w[4];
#pragma unroll
    for (int i = 0; i < 4; ++i) a[i] = *(const float4*)(At + (nb + i) * 128 + k);
#pragma unroll
    for (int kk = 0; kk < 4; ++kk)
      w[kk] = *(const float4*)(Wt + (k + kk) * 64 + fbase);
#pragma unroll
    for (int i = 0; i < 4; ++i) {
      acc[i][0] = fmaf(a[i].x, w[0].x, acc[i][0]);
      acc[i][1] = fmaf(a[i].x, w[0].y, acc[i][1]);
      acc[i][2] = fmaf(a[i].x, w[0].z, acc[i][2]);
      acc[i][3] = fmaf(a[i].x, w[0].w, acc[i][3]);
      acc[i][0] = fmaf(a[i].y, w[1].x, acc[i][0]);
      acc[i][1] = fmaf(a[i].y, w[1].y, acc[i][1]);
      acc[i][2] = fmaf(a[i].y, w[1].z, acc[i][2]);
      acc[i][3] = fmaf(a[i].y, w[1].w, acc[i][3]);
      acc[i][0] = fmaf(a[i].z, w[2].x, acc[i][0]);
      acc[i][1] = fmaf(a[i].z, w[2].y, acc[i][1]);
      acc[i][2] = fmaf(a[i].z, w[2].z, acc[i][2]);
      acc[i][3] = fmaf(a[i].z, w[2].w, acc[i][3]);
      acc[i][0] = fmaf(a[i].w, w[3].x, acc[i][0]);
      acc[i][1] = fmaf(a[i].w, w[3].y, acc[i][1]);
      acc[i][2] = fmaf(a[i].w, w[3].z, acc[i][2]);
      acc[i][3] = fmaf(a[i].w, w[3].w, acc[i][3]);
    }
  }

#pragma unroll
  for (int i = 0; i < 4; ++i) {
    const int node = nodebase + nb + i;
    if (node < n_nodes)
      *(float4*)(outmean + (size_t)node * FDIM + fbase) =
          make_float4(acc[i][0], acc[i][1], acc[i][2], acc[i][3]);
  }
}

extern "C" void kernel_launch(void* const* d_in, const int* in_sizes, int n_in,
                              void* d_out, int out_size, void* d_ws, size_t ws_size,
                              hipStream_t stream) {
  const float* x = (const float*)d_in[0];
  const int* edge_index = (const int*)d_in[1];
  const float* Wl = (const float*)d_in[2];
  const float* Wr = (const float*)d_in[3];
  float* out = (float*)d_out;

  const int n_nodes = in_sizes[0] / FDIM;  // 100000
  const int n_edges = in_sizes[1] / 2;     // 1200000
  const int* e_src = edge_index;
  const int* e_dst = edge_index + n_edges;

  const int NB = (n_nodes + SCAN_BS - 1) / SCAN_BS;  // 98
  const int NBKT = (n_nodes + NPB - 1) / NPB;        // 98

  // ws layout (ints; pairs 8B-aligned)
  int* deg = (int*)d_ws;                 // N
  int* bsum = deg + n_nodes;             // SCAN_BS
  int* offsets = bsum + SCAN_BS;         // N+1
  int* cursorB = offsets + n_nodes + 2;  // MAXBKT
  int* praw = cursorB + MAXBKT;
  int2* pairs = (int2*)(((uintptr_t)praw + 7) & ~(uintptr_t)7);  // E pairs
  int* sorted_src = (int*)(pairs + n_edges);                     // E

  hipMemsetAsync(deg, 0, (size_t)n_nodes * sizeof(int), stream);

  k_hist<<<(n_edges + 255) / 256, 256, 0, stream>>>(e_dst, deg, n_edges);
  k_blocksum<<<NB, SCAN_BS, 0, stream>>>(deg, bsum, n_nodes);
  k_scanbsum<<<1, SCAN_BS, 0, stream>>>(bsum, NB);
  k_scan<<<NB, SCAN_BS, 0, stream>>>(deg, bsum, offsets, n_nodes, n_edges);
  k_initB<<<1, MAXBKT, 0, stream>>>(offsets, cursorB, NBKT, n_nodes);
  k_part<<<(n_edges + PART_T - 1) / PART_T, 256, 0, stream>>>(e_src, e_dst, cursorB,
                                                              pairs, n_edges);
  k_sub<<<NBKT, 256, 0, stream>>>(pairs, offsets, sorted_src, n_nodes);
  k_agg<<<(n_nodes + 3) / 4, 256, 0, stream>>>(x, offsets, sorted_src, out, n_nodes);
  k_gemm<<<(n_nodes + 63) / 64, 256, 0, stream>>>(x, Wl, Wr, out, n_nodes);
}

// Round 6
// 259.566 us; speedup vs baseline: 2.2761x; 1.0701x over previous
//
#include <hip/hip_runtime.h>
#include <stdint.h>

// SAGEConv (mean aggr, no bias): out = segment_mean(x[src], dst) @ W_l + x @ W_r
// Pipeline: degree hist -> scan -> two-level partition (bucket by dst>>10, then
// L2-local sub-scatter) -> gather-mean (wave/node, float4) emitting bf16
// mean/x -> MFMA bf16 GEMM out = [mean|x] @ [Wl;Wr] (fp32 accumulate).

#define FDIM 64
#define SCAN_BS 1024
#define NPB 1024
#define PART_T 2048
#define MAXBKT 128

typedef __attribute__((ext_vector_type(8))) short bf16x8;
typedef __attribute__((ext_vector_type(4))) float f32x4;

__device__ inline ushort f2b(float v) {
  union { float f; uint32_t u; } c; c.f = v;
  return (ushort)((c.u + 0x7FFF + ((c.u >> 16) & 1)) >> 16);  // RNE
}

// ---- A: degree histogram ----
__global__ __launch_bounds__(256) void k_hist(const int* __restrict__ dst,
                                              int* __restrict__ deg, int E) {
  int i = blockIdx.x * 256 + threadIdx.x;
  if (i < E) atomicAdd(&deg[dst[i]], 1);
}

// ---- B: per-block sums of deg ----
__global__ __launch_bounds__(SCAN_BS) void k_blocksum(const int* __restrict__ deg,
                                                      int* __restrict__ bsum, int N) {
  __shared__ int lds[SCAN_BS];
  int i = blockIdx.x * SCAN_BS + threadIdx.x;
  lds[threadIdx.x] = (i < N) ? deg[i] : 0;
  __syncthreads();
  for (int off = SCAN_BS / 2; off > 0; off >>= 1) {
    if (threadIdx.x < off) lds[threadIdx.x] += lds[threadIdx.x + off];
    __syncthreads();
  }
  if (threadIdx.x == 0) bsum[blockIdx.x] = lds[0];
}

// ---- C: exclusive scan of the (<=1024) block sums ----
__global__ __launch_bounds__(SCAN_BS) void k_scanbsum(int* __restrict__ bsum, int NB) {
  __shared__ int lds[SCAN_BS];
  int t = threadIdx.x;
  lds[t] = (t < NB) ? bsum[t] : 0;
  __syncthreads();
  if (t == 0) {
    int run = 0;
    for (int i = 0; i < NB; ++i) { int v = lds[i]; lds[i] = run; run += v; }
  }
  __syncthreads();
  if (t < NB) bsum[t] = lds[t];
}

// ---- D: per-block exclusive scan + block offset -> offsets ----
__global__ __launch_bounds__(SCAN_BS) void k_scan(const int* __restrict__ deg,
                                                  const int* __restrict__ bsum,
                                                  int* __restrict__ offsets,
                                                  int N, int E) {
  __shared__ int lds[SCAN_BS];
  int i = blockIdx.x * SCAN_BS + threadIdx.x;
  int v = (i < N) ? deg[i] : 0;
  lds[threadIdx.x] = v;
  __syncthreads();
  for (int off = 1; off < SCAN_BS; off <<= 1) {
    int add = (threadIdx.x >= off) ? lds[threadIdx.x - off] : 0;
    __syncthreads();
    lds[threadIdx.x] += add;
    __syncthreads();
  }
  int excl = lds[threadIdx.x] - v + bsum[blockIdx.x];
  if (i < N) offsets[i] = excl;
  if (i == 0) offsets[N] = E;
}

// ---- D2: init per-bucket global cursors from offsets ----
__global__ void k_initB(const int* __restrict__ offsets, int* __restrict__ cursorB,
                        int nbkt, int n_nodes) {
  int t = threadIdx.x;
  if (t < nbkt) cursorB[t] = offsets[min(t * NPB, n_nodes)];
}

// ---- W transpose + bf16 convert: WlT[f][k] = Wl[k][f] ----
__global__ __launch_bounds__(256) void k_cvtW(const float* __restrict__ Wl,
                                              const float* __restrict__ Wr,
                                              ushort* __restrict__ WlT,
                                              ushort* __restrict__ WrT) {
  int idx = blockIdx.x * 256 + threadIdx.x;  // 0..4095
  int f = idx >> 6, k = idx & 63;
  WlT[f * 64 + k] = f2b(Wl[k * 64 + f]);
  WrT[f * 64 + k] = f2b(Wr[k * 64 + f]);
}

// ---- E1: partition edges into dst-buckets (coalesced run writes) ----
__global__ __launch_bounds__(256) void k_part(const int* __restrict__ esrc,
                                              const int* __restrict__ edst,
                                              int* __restrict__ cursorB,
                                              int2* __restrict__ pairs, int E) {
  __shared__ int cnt[MAXBKT], excl0[MAXBKT], cursorL[MAXBKT], gbase[MAXBKT];
  __shared__ int sc[MAXBKT];
  __shared__ int2 buf[PART_T];
  const int t = threadIdx.x;
  const int base = blockIdx.x * PART_T;
  const int nvalid = min(E - base, PART_T);

  for (int b = t; b < MAXBKT; b += 256) cnt[b] = 0;
  __syncthreads();

  int s[8], d[8], bk[8];
#pragma unroll
  for (int i = 0; i < 8; ++i) {
    const int e = base + i * 256 + t;
    if (e < E) {
      s[i] = esrc[e];
      d[i] = edst[e];
      bk[i] = d[i] >> 10;
      atomicAdd(&cnt[bk[i]], 1);
    } else {
      bk[i] = -1;
    }
  }
  __syncthreads();

  if (t < MAXBKT) sc[t] = cnt[t];
  __syncthreads();
  for (int off = 1; off < MAXBKT; off <<= 1) {
    int v = 0;
    if (t < MAXBKT && t >= off) v = sc[t - off];
    __syncthreads();
    if (t < MAXBKT) sc[t] += v;
    __syncthreads();
  }
  if (t < MAXBKT) {
    excl0[t] = sc[t] - cnt[t];
    cursorL[t] = excl0[t];
  }
  __syncthreads();

#pragma unroll
  for (int i = 0; i < 8; ++i) {
    if (bk[i] >= 0) {
      int slot = atomicAdd(&cursorL[bk[i]], 1);
      buf[slot] = make_int2(s[i], d[i]);
    }
  }
  __syncthreads();

  if (t < MAXBKT && cnt[t] > 0) gbase[t] = atomicAdd(&cursorB[t], cnt[t]);
  __syncthreads();

  for (int idx = t; idx < nvalid; idx += 256) {
    int2 p = buf[idx];
    int b = p.y >> 10;
    pairs[gbase[b] + (idx - excl0[b])] = p;
  }
}

// ---- E2: within-bucket scatter to final CSR order (L2-local writes) ----
__global__ __launch_bounds__(256) void k_sub(const int2* __restrict__ pairs,
                                             const int* __restrict__ offsets,
                                             int* __restrict__ sorted_src,
                                             int n_nodes) {
  __shared__ int cur[NPB];
  const int nodebase = blockIdx.x * NPB;
  const int nodeend = min(nodebase + NPB, n_nodes);
  for (int i = threadIdx.x; i < NPB; i += 256) cur[i] = 0;
  __syncthreads();
  const int rstart = offsets[nodebase];
  const int rend = offsets[nodeend];
  for (int i = rstart + threadIdx.x; i < rend; i += 256) {
    int2 p = pairs[i];
    int r = atomicAdd(&cur[p.y - nodebase], 1);
    sorted_src[offsets[p.y] + r] = p.x;
  }
}

// ---- F: gather-mean (wave/node, float4) -> bf16 meanb + bf16 xb ----
__global__ __launch_bounds__(256) void k_agg(const float* __restrict__ x,
                                             const int* __restrict__ offsets,
                                             const int* __restrict__ sorted_src,
                                             ushort* __restrict__ meanb,
                                             ushort* __restrict__ xb, int n_nodes) {
  const int node = blockIdx.x * 4 + (threadIdx.x >> 6);
  const int lane = threadIdx.x & 63;
  if (node >= n_nodes) return;

  const int c = lane & 15;
  const int g = lane >> 4;

  const int start = offsets[node];
  const int end = offsets[node + 1];
  const int degree = end - start;

  float4 s = make_float4(0.f, 0.f, 0.f, 0.f);

  for (int base = start; base < end; base += 64) {
    const int e = base + lane;
    const int idx = (e < end) ? sorted_src[e] : node;  // pad = safe address
    const int nIn = min(end - base, 64);
    const int G = (nIn + 3) >> 2;
#pragma unroll 4
    for (int j = 0; j < G; ++j) {
      const int sub = 4 * j + g;
      const int se = __shfl(idx, sub, 64);
      const float wm = (sub < nIn) ? 1.0f : 0.0f;
      const float4 v = *(const float4*)(x + (size_t)se * FDIM + (c << 2));
      s.x = fmaf(v.x, wm, s.x);
      s.y = fmaf(v.y, wm, s.y);
      s.z = fmaf(v.z, wm, s.z);
      s.w = fmaf(v.w, wm, s.w);
    }
  }

  s.x += __shfl_xor(s.x, 16, 64);
  s.y += __shfl_xor(s.y, 16, 64);
  s.z += __shfl_xor(s.z, 16, 64);
  s.w += __shfl_xor(s.w, 16, 64);
  s.x += __shfl_xor(s.x, 32, 64);
  s.y += __shfl_xor(s.y, 32, 64);
  s.z += __shfl_xor(s.z, 32, 64);
  s.w += __shfl_xor(s.w, 32, 64);

  if (g == 0) {
    const float inv = 1.0f / (float)max(degree, 1);
    ushort4 mb;
    mb.x = f2b(s.x * inv);
    mb.y = f2b(s.y * inv);
    mb.z = f2b(s.z * inv);
    mb.w = f2b(s.w * inv);
    *(ushort4*)(meanb + (size_t)node * FDIM + (c << 2)) = mb;
  } else if (g == 1) {
    const float4 xv = *(const float4*)(x + (size_t)node * FDIM + (c << 2));
    ushort4 xo;
    xo.x = f2b(xv.x);
    xo.y = f2b(xv.y);
    xo.z = f2b(xv.z);
    xo.w = f2b(xv.w);
    *(ushort4*)(xb + (size_t)node * FDIM + (c << 2)) = xo;
  }
}

// ---- G: MFMA bf16 GEMM  out = meanb @ Wl + xb @ Wr (fp32 acc, no LDS) ----
// Wave per 16 nodes. A[m][k]: m=lane&15, k=half*8+j (half=lane>>4).
// B[k][n]: n=lane&15, k=half*8+j -> contiguous in WT[f][k].
// C/D: col=lane&15 (=f), row=half*4+reg (=node).
__global__ __launch_bounds__(256) void k_gemm(const ushort* __restrict__ meanb,
                                              const ushort* __restrict__ xb,
                                              const ushort* __restrict__ WlT,
                                              const ushort* __restrict__ WrT,
                                              float* __restrict__ out, int n_nodes) {
  const int wave = __builtin_amdgcn_readfirstlane(threadIdx.x >> 6);
  const int lane = threadIdx.x & 63;
  const int m = lane & 15;
  const int half = lane >> 4;
  const int nodebase = blockIdx.x * 64 + wave * 16;
  if (nodebase >= n_nodes) return;

  const int arow = min(nodebase + m, n_nodes - 1);
  bf16x8 am0 = *(const bf16x8*)(meanb + (size_t)arow * FDIM + half * 8);
  bf16x8 am1 = *(const bf16x8*)(meanb + (size_t)arow * FDIM + 32 + half * 8);
  bf16x8 ax0 = *(const bf16x8*)(xb + (size_t)arow * FDIM + half * 8);
  bf16x8 ax1 = *(const bf16x8*)(xb + (size_t)arow * FDIM + 32 + half * 8);

#pragma unroll
  for (int fc = 0; fc < 4; ++fc) {
    const int f = fc * 16 + m;
    bf16x8 bl0 = *(const bf16x8*)(WlT + (size_t)f * FDIM + half * 8);
    bf16x8 bl1 = *(const bf16x8*)(WlT + (size_t)f * FDIM + 32 + half * 8);
    bf16x8 br0 = *(const bf16x8*)(WrT + (size_t)f * FDIM + half * 8);
    bf16x8 br1 = *(const bf16x8*)(WrT + (size_t)f * FDIM + 32 + half * 8);
    f32x4 acc = {0.f, 0.f, 0.f, 0.f};
    acc = __builtin_amdgcn_mfma_f32_16x16x32_bf16(am0, bl0, acc, 0, 0, 0);
    acc = __builtin_amdgcn_mfma_f32_16x16x32_bf16(am1, bl1, acc, 0, 0, 0);
    acc = __builtin_amdgcn_mfma_f32_16x16x32_bf16(ax0, br0, acc, 0, 0, 0);
    acc = __builtin_amdgcn_mfma_f32_16x16x32_bf16(ax1, br1, acc, 0, 0, 0);
#pragma unroll
    for (int r = 0; r < 4; ++r) {
      const int node = nodebase + half * 4 + r;
      if (node < n_nodes) out[(size_t)node * FDIM + fc * 16 + m] = acc[r];
    }
  }
}

extern "C" void kernel_launch(void* const* d_in, const int* in_sizes, int n_in,
                              void* d_out, int out_size, void* d_ws, size_t ws_size,
                              hipStream_t stream) {
  const float* x = (const float*)d_in[0];
  const int* edge_index = (const int*)d_in[1];
  const float* Wl = (const float*)d_in[2];
  const float* Wr = (const float*)d_in[3];
  float* out = (float*)d_out;

  const int n_nodes = in_sizes[0] / FDIM;  // 100000
  const int n_edges = in_sizes[1] / 2;     // 1200000
  const int* e_src = edge_index;
  const int* e_dst = edge_index + n_edges;

  const int NB = (n_nodes + SCAN_BS - 1) / SCAN_BS;  // 98
  const int NBKT = (n_nodes + NPB - 1) / NPB;        // 98

  // ws layout
  int* deg = (int*)d_ws;                 // N
  int* bsum = deg + n_nodes;             // SCAN_BS
  int* offsets = bsum + SCAN_BS;         // N+1
  int* cursorB = offsets + n_nodes + 2;  // MAXBKT
  int* praw = cursorB + MAXBKT;
  int2* pairs = (int2*)(((uintptr_t)praw + 15) & ~(uintptr_t)15);  // E pairs
  int* sorted_src = (int*)(pairs + n_edges);                       // E
  ushort* meanb = (ushort*)(((uintptr_t)(sorted_src + n_edges) + 15) &
                            ~(uintptr_t)15);         // N*64 bf16
  ushort* xbuf = meanb + (size_t)n_nodes * FDIM;     // N*64 bf16
  ushort* WlT = xbuf + (size_t)n_nodes * FDIM;       // 4096
  ushort* WrT = WlT + FDIM * FDIM;                   // 4096

  hipMemsetAsync(deg, 0, (size_t)n_nodes * sizeof(int), stream);

  k_cvtW<<<16, 256, 0, stream>>>(Wl, Wr, WlT, WrT);
  k_hist<<<(n_edges + 255) / 256, 256, 0, stream>>>(e_dst, deg, n_edges);
  k_blocksum<<<NB, SCAN_BS, 0, stream>>>(deg, bsum, n_nodes);
  k_scanbsum<<<1, SCAN_BS, 0, stream>>>(bsum, NB);
  k_scan<<<NB, SCAN_BS, 0, stream>>>(deg, bsum, offsets, n_nodes, n_edges);
  k_initB<<<1, MAXBKT, 0, stream>>>(offsets, cursorB, NBKT, n_nodes);
  k_part<<<(n_edges + PART_T - 1) / PART_T, 256, 0, stream>>>(e_src, e_dst, cursorB,
                                                              pairs, n_edges);
  k_sub<<<NBKT, 256, 0, stream>>>(pairs, offsets, sorted_src, n_nodes);
  k_agg<<<(n_nodes + 3) / 4, 256, 0, stream>>>(x, offsets, sorted_src, meanb, xbuf,
                                               n_nodes);
  k_gemm<<<(n_nodes + 63) / 64, 256, 0, stream>>>(meanb, xbuf, WlT, WrT, out,
                                                  n_nodes);
}

// Round 7
// 202.756 us; speedup vs baseline: 2.9138x; 1.2802x over previous
//
#include <hip/hip_runtime.h>
#include <stdint.h>

// SAGEConv (mean aggr, no bias): out = segment_mean(x[src], dst) @ W_l + x @ W_r
// Pipeline (7 dispatches):
//   k_cvt  : x -> bf16 xb, Wl/Wr -> transposed bf16, zero bucket counters
//   k_cnt  : per-bucket (dst>>10) edge counts (LDS-aggregated)
//   k_scanB: scan 98 bucket counts -> bktBase, cursorB; offsets[N]=E
//   k_part : partition edges into dst-buckets (coalesced run writes)
//   k_sub  : per bucket: node counts -> LDS scan -> offsets + CSR scatter
//   k_agg  : gather-mean over bf16 rows (wave/node) -> bf16 meanb
//   k_gemm : MFMA bf16 out = meanb@Wl + xb@Wr (fp32 acc)

#define FDIM 64
#define NPB 1024
#define PART_T 2048
#define MAXBKT 128

typedef __attribute__((ext_vector_type(8))) short bf16x8;
typedef __attribute__((ext_vector_type(4))) float f32x4;

__device__ inline ushort f2b(float v) {
  union { float f; uint32_t u; } c; c.f = v;
  return (ushort)((c.u + 0x7FFF + ((c.u >> 16) & 1)) >> 16);  // RNE
}
__device__ inline float b2f(ushort h) {
  union { uint32_t u; float f; } c; c.u = ((uint32_t)h) << 16;
  return c.f;
}

// ---- 1: x -> bf16, W transpose -> bf16, zero bucket counters ----
__global__ __launch_bounds__(256) void k_cvt(const float* __restrict__ x,
                                             const float* __restrict__ Wl,
                                             const float* __restrict__ Wr,
                                             ushort* __restrict__ xb,
                                             ushort* __restrict__ WlT,
                                             ushort* __restrict__ WrT,
                                             int* __restrict__ bktCnt, int xquads) {
  const int bid = blockIdx.x;
  const int t = threadIdx.x;
  if (bid == 0 && t < MAXBKT) bktCnt[t] = 0;
  const int XB = (xquads + 255) / 256;
  if (bid < XB) {
    const int idx = bid * 256 + t;
    if (idx < xquads) {
      const float4 v = ((const float4*)x)[idx];
      ushort4 o;
      o.x = f2b(v.x); o.y = f2b(v.y); o.z = f2b(v.z); o.w = f2b(v.w);
      ((ushort4*)xb)[idx] = o;
    }
  } else {
    const int idx = (bid - XB) * 256 + t;  // 0..4095
    const int f = idx >> 6, k = idx & 63;
    WlT[f * 64 + k] = f2b(Wl[k * 64 + f]);
    WrT[f * 64 + k] = f2b(Wr[k * 64 + f]);
  }
}

// ---- 2: bucket counts ----
__global__ __launch_bounds__(256) void k_cnt(const int* __restrict__ edst,
                                             int* __restrict__ bktCnt, int E) {
  __shared__ int cnt[MAXBKT];
  const int t = threadIdx.x;
  const int base = blockIdx.x * PART_T;
  for (int b = t; b < MAXBKT; b += 256) cnt[b] = 0;
  __syncthreads();
#pragma unroll
  for (int i = 0; i < 8; ++i) {
    const int e = base + i * 256 + t;
    if (e < E) atomicAdd(&cnt[edst[e] >> 10], 1);
  }
  __syncthreads();
  for (int b = t; b < MAXBKT; b += 256)
    if (cnt[b]) atomicAdd(&bktCnt[b], cnt[b]);
}

// ---- 3: scan bucket counts -> bktBase, cursorB; offsets[N]=E ----
__global__ void k_scanB(const int* __restrict__ bktCnt, int* __restrict__ bktBase,
                        int* __restrict__ cursorB, int* __restrict__ offsets,
                        int nbkt, int N, int E) {
  __shared__ int base_s[MAXBKT + 1];
  const int t = threadIdx.x;
  if (t == 0) {
    int run = 0;
    for (int i = 0; i < nbkt; ++i) { base_s[i] = run; run += bktCnt[i]; }
    base_s[nbkt] = run;
  }
  __syncthreads();
  if (t <= nbkt) {
    bktBase[t] = base_s[t];
    if (t < nbkt) cursorB[t] = base_s[t];
  }
  if (t == 0) offsets[N] = E;
}

// ---- 4: partition edges into dst-buckets (coalesced run writes) ----
__global__ __launch_bounds__(256) void k_part(const int* __restrict__ esrc,
                                              const int* __restrict__ edst,
                                              int* __restrict__ cursorB,
                                              int2* __restrict__ pairs, int E) {
  __shared__ int cnt[MAXBKT], excl0[MAXBKT], cursorL[MAXBKT], gbase[MAXBKT];
  __shared__ int sc[MAXBKT];
  __shared__ int2 buf[PART_T];
  const int t = threadIdx.x;
  const int base = blockIdx.x * PART_T;
  const int nvalid = min(E - base, PART_T);

  for (int b = t; b < MAXBKT; b += 256) cnt[b] = 0;
  __syncthreads();

  int s[8], d[8], bk[8];
#pragma unroll
  for (int i = 0; i < 8; ++i) {
    const int e = base + i * 256 + t;
    if (e < E) {
      s[i] = esrc[e];
      d[i] = edst[e];
      bk[i] = d[i] >> 10;
      atomicAdd(&cnt[bk[i]], 1);
    } else {
      bk[i] = -1;
    }
  }
  __syncthreads();

  if (t < MAXBKT) sc[t] = cnt[t];
  __syncthreads();
  for (int off = 1; off < MAXBKT; off <<= 1) {
    int v = 0;
    if (t < MAXBKT && t >= off) v = sc[t - off];
    __syncthreads();
    if (t < MAXBKT) sc[t] += v;
    __syncthreads();
  }
  if (t < MAXBKT) {
    excl0[t] = sc[t] - cnt[t];
    cursorL[t] = excl0[t];
  }
  __syncthreads();

#pragma unroll
  for (int i = 0; i < 8; ++i) {
    if (bk[i] >= 0) {
      int slot = atomicAdd(&cursorL[bk[i]], 1);
      buf[slot] = make_int2(s[i], d[i]);
    }
  }
  __syncthreads();

  if (t < MAXBKT && cnt[t] > 0) gbase[t] = atomicAdd(&cursorB[t], cnt[t]);
  __syncthreads();

  for (int idx = t; idx < nvalid; idx += 256) {
    int2 p = buf[idx];
    int b = p.y >> 10;
    pairs[gbase[b] + (idx - excl0[b])] = p;
  }
}

// ---- 5: per bucket: count -> scan -> offsets + CSR scatter (L2-local) ----
__global__ __launch_bounds__(1024) void k_sub(const int2* __restrict__ pairs,
                                              const int* __restrict__ bktBase,
                                              int* __restrict__ offsets,
                                              int* __restrict__ sorted_src,
                                              int n_nodes) {
  __shared__ int cnt[NPB];
  const int b = blockIdx.x;
  const int t = threadIdx.x;
  const int nodebase = b * NPB;
  const int rstart = bktBase[b], rend = bktBase[b + 1];
  cnt[t] = 0;
  __syncthreads();
  for (int i = rstart + t; i < rend; i += 1024) {
    int2 p = pairs[i];
    atomicAdd(&cnt[p.y - nodebase], 1);
  }
  __syncthreads();
  const int v = cnt[t];
  for (int off = 1; off < NPB; off <<= 1) {
    int add = (t >= off) ? cnt[t - off] : 0;
    __syncthreads();
    cnt[t] += add;
    __syncthreads();
  }
  const int gpos = rstart + cnt[t] - v;  // node's global CSR start
  const int node = nodebase + t;
  if (node < n_nodes) offsets[node] = gpos;
  __syncthreads();
  cnt[t] = gpos;  // reuse as global cursor
  __syncthreads();
  for (int i = rstart + t; i < rend; i += 1024) {
    int2 p = pairs[i];
    int pos = atomicAdd(&cnt[p.y - nodebase], 1);
    sorted_src[pos] = p.x;
  }
}

// ---- 6: gather-mean over bf16 rows (wave/node) -> bf16 meanb ----
// c = lane & 15 (8 B slice of the 128 B row), g = lane >> 4 (edge slot 0..3).
__global__ __launch_bounds__(256) void k_agg(const ushort* __restrict__ xb,
                                             const int* __restrict__ offsets,
                                             const int* __restrict__ sorted_src,
                                             ushort* __restrict__ meanb,
                                             int n_nodes) {
  const int node = blockIdx.x * 4 + (threadIdx.x >> 6);
  const int lane = threadIdx.x & 63;
  if (node >= n_nodes) return;

  const int c = lane & 15;
  const int g = lane >> 4;

  const int start = offsets[node];
  const int end = offsets[node + 1];
  const int degree = end - start;

  float s0 = 0.f, s1 = 0.f, s2 = 0.f, s3 = 0.f;

  for (int base = start; base < end; base += 64) {
    const int e = base + lane;
    const int idx = (e < end) ? sorted_src[e] : node;  // pad = safe address
    const int nIn = min(end - base, 64);
    const int G = (nIn + 3) >> 2;
#pragma unroll 4
    for (int j = 0; j < G; ++j) {
      const int sub = 4 * j + g;
      const int se = __shfl(idx, sub, 64);
      const float wm = (sub < nIn) ? 1.0f : 0.0f;
      const ushort4 h = *(const ushort4*)(xb + (size_t)se * FDIM + (c << 2));
      s0 = fmaf(b2f(h.x), wm, s0);
      s1 = fmaf(b2f(h.y), wm, s1);
      s2 = fmaf(b2f(h.z), wm, s2);
      s3 = fmaf(b2f(h.w), wm, s3);
    }
  }

  s0 += __shfl_xor(s0, 16, 64);
  s1 += __shfl_xor(s1, 16, 64);
  s2 += __shfl_xor(s2, 16, 64);
  s3 += __shfl_xor(s3, 16, 64);
  s0 += __shfl_xor(s0, 32, 64);
  s1 += __shfl_xor(s1, 32, 64);
  s2 += __shfl_xor(s2, 32, 64);
  s3 += __shfl_xor(s3, 32, 64);

  if (g == 0) {
    const float inv = 1.0f / (float)max(degree, 1);
    ushort4 mb;
    mb.x = f2b(s0 * inv);
    mb.y = f2b(s1 * inv);
    mb.z = f2b(s2 * inv);
    mb.w = f2b(s3 * inv);
    *(ushort4*)(meanb + (size_t)node * FDIM + (c << 2)) = mb;
  }
}

// ---- 7: MFMA bf16 GEMM  out = meanb @ Wl + xb @ Wr (fp32 acc, no LDS) ----
__global__ __launch_bounds__(256) void k_gemm(const ushort* __restrict__ meanb,
                                              const ushort* __restrict__ xb,
                                              const ushort* __restrict__ WlT,
                                              const ushort* __restrict__ WrT,
                                              float* __restrict__ out, int n_nodes) {
  const int wave = __builtin_amdgcn_readfirstlane(threadIdx.x >> 6);
  const int lane = threadIdx.x & 63;
  const int m = lane & 15;
  const int half = lane >> 4;
  const int nodebase = blockIdx.x * 64 + wave * 16;
  if (nodebase >= n_nodes) return;

  const int arow = min(nodebase + m, n_nodes - 1);
  bf16x8 am0 = *(const bf16x8*)(meanb + (size_t)arow * FDIM + half * 8);
  bf16x8 am1 = *(const bf16x8*)(meanb + (size_t)arow * FDIM + 32 + half * 8);
  bf16x8 ax0 = *(const bf16x8*)(xb + (size_t)arow * FDIM + half * 8);
  bf16x8 ax1 = *(const bf16x8*)(xb + (size_t)arow * FDIM + 32 + half * 8);

#pragma unroll
  for (int fc = 0; fc < 4; ++fc) {
    const int f = fc * 16 + m;
    bf16x8 bl0 = *(const bf16x8*)(WlT + (size_t)f * FDIM + half * 8);
    bf16x8 bl1 = *(const bf16x8*)(WlT + (size_t)f * FDIM + 32 + half * 8);
    bf16x8 br0 = *(const bf16x8*)(WrT + (size_t)f * FDIM + half * 8);
    bf16x8 br1 = *(const bf16x8*)(WrT + (size_t)f * FDIM + 32 + half * 8);
    f32x4 acc = {0.f, 0.f, 0.f, 0.f};
    acc = __builtin_amdgcn_mfma_f32_16x16x32_bf16(am0, bl0, acc, 0, 0, 0);
    acc = __builtin_amdgcn_mfma_f32_16x16x32_bf16(am1, bl1, acc, 0, 0, 0);
    acc = __builtin_amdgcn_mfma_f32_16x16x32_bf16(ax0, br0, acc, 0, 0, 0);
    acc = __builtin_amdgcn_mfma_f32_16x16x32_bf16(ax1, br1, acc, 0, 0, 0);
#pragma unroll
    for (int r = 0; r < 4; ++r) {
      const int node = nodebase + half * 4 + r;
      if (node < n_nodes) out[(size_t)node * FDIM + fc * 16 + m] = acc[r];
    }
  }
}

extern "C" void kernel_launch(void* const* d_in, const int* in_sizes, int n_in,
                              void* d_out, int out_size, void* d_ws, size_t ws_size,
                              hipStream_t stream) {
  const float* x = (const float*)d_in[0];
  const int* edge_index = (const int*)d_in[1];
  const float* Wl = (const float*)d_in[2];
  const float* Wr = (const float*)d_in[3];
  float* out = (float*)d_out;

  const int n_nodes = in_sizes[0] / FDIM;  // 100000
  const int n_edges = in_sizes[1] / 2;     // 1200000
  const int* e_src = edge_index;
  const int* e_dst = edge_index + n_edges;

  const int NBKT = (n_nodes + NPB - 1) / NPB;  // 98

  // ws layout
  int* bktCnt = (int*)d_ws;                 // MAXBKT
  int* bktBase = bktCnt + MAXBKT;           // MAXBKT+1
  int* cursorB = bktBase + MAXBKT + 1;      // MAXBKT
  int* offsets = cursorB + MAXBKT;          // N+1
  int* praw = offsets + n_nodes + 2;
  int2* pairs = (int2*)(((uintptr_t)praw + 15) & ~(uintptr_t)15);  // E
  int* sorted_src = (int*)(pairs + n_edges);                       // E
  ushort* xbuf = (ushort*)(((uintptr_t)(sorted_src + n_edges) + 15) &
                           ~(uintptr_t)15);        // N*64 bf16
  ushort* meanb = xbuf + (size_t)n_nodes * FDIM;   // N*64 bf16
  ushort* WlT = meanb + (size_t)n_nodes * FDIM;    // 4096
  ushort* WrT = WlT + FDIM * FDIM;                 // 4096

  const int xquads = n_nodes * (FDIM / 4);  // 1.6M float4 units
  const int XB = (xquads + 255) / 256;
  const int EB = (n_edges + PART_T - 1) / PART_T;

  k_cvt<<<XB + 16, 256, 0, stream>>>(x, Wl, Wr, xbuf, WlT, WrT, bktCnt, xquads);
  k_cnt<<<EB, 256, 0, stream>>>(e_dst, bktCnt, n_edges);
  k_scanB<<<1, 128, 0, stream>>>(bktCnt, bktBase, cursorB, offsets, NBKT, n_nodes,
                                 n_edges);
  k_part<<<EB, 256, 0, stream>>>(e_src, e_dst, cursorB, pairs, n_edges);
  k_sub<<<NBKT, 1024, 0, stream>>>(pairs, bktBase, offsets, sorted_src, n_nodes);
  k_agg<<<(n_nodes + 3) / 4, 256, 0, stream>>>(xbuf, offsets, sorted_src, meanb,
                                               n_nodes);
  k_gemm<<<(n_nodes + 63) / 64, 256, 0, stream>>>(meanb, xbuf, WlT, WrT, out,
                                                  n_nodes);
}

// Round 8
// 175.883 us; speedup vs baseline: 3.3590x; 1.1528x over previous
//
#include <hip/hip_runtime.h>
#include <stdint.h>

// SAGEConv (mean aggr, no bias): out = segment_mean(x[src], dst) @ W_l + x @ W_r
// Pipeline (4 dispatches):
//   k_cvt  : x -> bf16 xb, Wl/Wr -> transposed bf16, cursorB[b]=b*CAP, offsets[N]=E
//   k_part : partition edges into padded dst-buckets (dst>>9); counts fall out
//            of cursorB as a byproduct
//   k_sub  : per bucket: derive counts -> csr base -> node scan -> offsets + CSR
//   k_fused: gather-mean (wave/node-quad) -> LDS bf16 tile -> MFMA GEMM
//            out = mean@Wl + x@Wr (fp32 acc)

#define FDIM 64
#define NPB 512
#define PART_T 2048
#define MAXBKT 256
#define CAP 8192

typedef __attribute__((ext_vector_type(8))) short bf16x8;
typedef __attribute__((ext_vector_type(4))) float f32x4;

__device__ inline ushort f2b(float v) {
  union { float f; uint32_t u; } c; c.f = v;
  return (ushort)((c.u + 0x7FFF + ((c.u >> 16) & 1)) >> 16);  // RNE
}
__device__ inline float b2f(ushort h) {
  union { uint32_t u; float f; } c; c.u = ((uint32_t)h) << 16;
  return c.f;
}

// ---- 1: x -> bf16, W transpose -> bf16, cursor init ----
__global__ __launch_bounds__(256) void k_cvt(const float* __restrict__ x,
                                             const float* __restrict__ Wl,
                                             const float* __restrict__ Wr,
                                             ushort* __restrict__ xb,
                                             ushort* __restrict__ WlT,
                                             ushort* __restrict__ WrT,
                                             int* __restrict__ cursorB,
                                             int* __restrict__ offsets, int xquads,
                                             int XB, int N, int E) {
  const int bid = blockIdx.x;
  const int t = threadIdx.x;
  if (bid < XB) {
    const int idx = bid * 256 + t;
    if (idx < xquads) {
      const float4 v = ((const float4*)x)[idx];
      ushort4 o;
      o.x = f2b(v.x); o.y = f2b(v.y); o.z = f2b(v.z); o.w = f2b(v.w);
      ((ushort4*)xb)[idx] = o;
    }
  } else {
    const int idx = (bid - XB) * 256 + t;  // 0..4095
    const int f = idx >> 6, k = idx & 63;
    WlT[f * 64 + k] = f2b(Wl[k * 64 + f]);
    WrT[f * 64 + k] = f2b(Wr[k * 64 + f]);
    if (bid == XB) cursorB[t] = t * CAP;  // 256 threads cover MAXBKT
    if (bid == XB + 1 && t == 0) offsets[N] = E;
  }
}

// ---- 2: partition edges into padded dst-buckets (coalesced run writes) ----
__global__ __launch_bounds__(256) void k_part(const int* __restrict__ esrc,
                                              const int* __restrict__ edst,
                                              int* __restrict__ cursorB,
                                              int2* __restrict__ pairs, int E) {
  __shared__ int cnt[MAXBKT], excl0[MAXBKT], cursorL[MAXBKT], gbase[MAXBKT];
  __shared__ int sc[MAXBKT];
  __shared__ int2 buf[PART_T];
  const int t = threadIdx.x;
  const int base = blockIdx.x * PART_T;
  const int nvalid = min(E - base, PART_T);

  for (int b = t; b < MAXBKT; b += 256) cnt[b] = 0;
  __syncthreads();

  int s[8], d[8], bk[8];
#pragma unroll
  for (int i = 0; i < 8; ++i) {
    const int e = base + i * 256 + t;
    if (e < E) {
      s[i] = esrc[e];
      d[i] = edst[e];
      bk[i] = d[i] >> 9;
      atomicAdd(&cnt[bk[i]], 1);
    } else {
      bk[i] = -1;
    }
  }
  __syncthreads();

  sc[t] = cnt[t];
  __syncthreads();
  for (int off = 1; off < MAXBKT; off <<= 1) {
    int v = (t >= off) ? sc[t - off] : 0;
    __syncthreads();
    sc[t] += v;
    __syncthreads();
  }
  excl0[t] = sc[t] - cnt[t];
  cursorL[t] = excl0[t];
  __syncthreads();

#pragma unroll
  for (int i = 0; i < 8; ++i) {
    if (bk[i] >= 0) {
      int slot = atomicAdd(&cursorL[bk[i]], 1);
      buf[slot] = make_int2(s[i], d[i]);
    }
  }
  __syncthreads();

  if (cnt[t] > 0) gbase[t] = atomicAdd(&cursorB[t], cnt[t]);
  __syncthreads();

  for (int idx = t; idx < nvalid; idx += 256) {
    int2 p = buf[idx];
    int b = p.y >> 9;
    pairs[gbase[b] + (idx - excl0[b])] = p;
  }
}

// ---- 3: per bucket: counts -> csr base -> node scan -> offsets + scatter ----
__global__ __launch_bounds__(512) void k_sub(const int2* __restrict__ pairs,
                                             const int* __restrict__ cursorB,
                                             int* __restrict__ offsets,
                                             int* __restrict__ sorted_src,
                                             int n_nodes, int nbkt) {
  __shared__ int scnt[MAXBKT];
  __shared__ int cnt[NPB];
  __shared__ int csr0_s;
  const int b = blockIdx.x;
  const int t = threadIdx.x;
  const int nodebase = b * NPB;
  if (t < MAXBKT) scnt[t] = (t < nbkt) ? (cursorB[t] - t * CAP) : 0;
  cnt[t] = 0;
  __syncthreads();
  const int mycnt = scnt[b];
  const int rbase = b * CAP;
  if (t == 0) {
    int run = 0;
    for (int i = 0; i < b; ++i) run += scnt[i];
    csr0_s = run;
  }
  for (int i = t; i < mycnt; i += 512) {
    atomicAdd(&cnt[pairs[rbase + i].y - nodebase], 1);
  }
  __syncthreads();
  const int v = cnt[t];
  for (int off = 1; off < NPB; off <<= 1) {
    int add = (t >= off) ? cnt[t - off] : 0;
    __syncthreads();
    cnt[t] += add;
    __syncthreads();
  }
  const int gpos = csr0_s + cnt[t] - v;  // node's global CSR start
  const int node = nodebase + t;
  if (node < n_nodes) offsets[node] = gpos;
  __syncthreads();
  cnt[t] = gpos;  // reuse as global cursor
  __syncthreads();
  for (int i = rbase + t; i < rbase + mycnt; i += 512) {
    int2 p = pairs[i];
    int pos = atomicAdd(&cnt[p.y - nodebase], 1);
    sorted_src[pos] = p.x;
  }
}

// ---- 4: fused gather-mean + MFMA GEMM (16 nodes / 256-thread block) ----
// Gather: wave w handles nodes w*4..w*4+3; lanes c=lane&15 (8B slice),
// g=lane>>4 (edge slot). Mean rows land in LDS (pad 72 -> 2-way max alias).
// MFMA: wave w computes feature slice [w*16, w*16+16) for all 16 nodes.
__global__ __launch_bounds__(256) void k_fused(const ushort* __restrict__ xb,
                                               const int* __restrict__ offsets,
                                               const int* __restrict__ sorted_src,
                                               const ushort* __restrict__ WlT,
                                               const ushort* __restrict__ WrT,
                                               float* __restrict__ out,
                                               int n_nodes) {
  __shared__ ushort meanLds[16][72];
  const int t = threadIdx.x;
  const int wave = t >> 6;
  const int lane = t & 63;
  const int c = lane & 15;
  const int g = lane >> 4;
  const int nodebase = blockIdx.x * 16;

#pragma unroll
  for (int q = 0; q < 4; ++q) {
    const int r = wave * 4 + q;
    const int node = nodebase + r;
    if (node >= n_nodes) break;
    const int start = offsets[node];
    const int end = offsets[node + 1];
    const int degree = end - start;

    float s0 = 0.f, s1 = 0.f, s2 = 0.f, s3 = 0.f;
    for (int base = start; base < end; base += 64) {
      const int e = base + lane;
      const int idx = (e < end) ? sorted_src[e] : node;  // pad = safe address
      const int nIn = min(end - base, 64);
      const int G = (nIn + 3) >> 2;
#pragma unroll 4
      for (int j = 0; j < G; ++j) {
        const int sub = 4 * j + g;
        const int se = __shfl(idx, sub, 64);
        const float wm = (sub < nIn) ? 1.0f : 0.0f;
        const ushort4 h = *(const ushort4*)(xb + (size_t)se * FDIM + (c << 2));
        s0 = fmaf(b2f(h.x), wm, s0);
        s1 = fmaf(b2f(h.y), wm, s1);
        s2 = fmaf(b2f(h.z), wm, s2);
        s3 = fmaf(b2f(h.w), wm, s3);
      }
    }
    s0 += __shfl_xor(s0, 16, 64);
    s1 += __shfl_xor(s1, 16, 64);
    s2 += __shfl_xor(s2, 16, 64);
    s3 += __shfl_xor(s3, 16, 64);
    s0 += __shfl_xor(s0, 32, 64);
    s1 += __shfl_xor(s1, 32, 64);
    s2 += __shfl_xor(s2, 32, 64);
    s3 += __shfl_xor(s3, 32, 64);
    if (g == 0) {
      const float inv = 1.0f / (float)max(degree, 1);
      ushort4 mb;
      mb.x = f2b(s0 * inv);
      mb.y = f2b(s1 * inv);
      mb.z = f2b(s2 * inv);
      mb.w = f2b(s3 * inv);
      *(ushort4*)(&meanLds[r][c << 2]) = mb;
    }
  }
  __syncthreads();

  // MFMA phase: A[m][k] m=lane&15, k=quad*8+j (quad=lane>>4); C col=m-slot
  const int m = lane & 15;
  const int quad = lane >> 4;
  bf16x8 am0 = *(const bf16x8*)(&meanLds[m][quad * 8]);
  bf16x8 am1 = *(const bf16x8*)(&meanLds[m][32 + quad * 8]);
  const int arow = min(nodebase + m, n_nodes - 1);
  bf16x8 ax0 = *(const bf16x8*)(xb + (size_t)arow * FDIM + quad * 8);
  bf16x8 ax1 = *(const bf16x8*)(xb + (size_t)arow * FDIM + 32 + quad * 8);
  const int f = wave * 16 + m;
  bf16x8 bl0 = *(const bf16x8*)(WlT + (size_t)f * FDIM + quad * 8);
  bf16x8 bl1 = *(const bf16x8*)(WlT + (size_t)f * FDIM + 32 + quad * 8);
  bf16x8 br0 = *(const bf16x8*)(WrT + (size_t)f * FDIM + quad * 8);
  bf16x8 br1 = *(const bf16x8*)(WrT + (size_t)f * FDIM + 32 + quad * 8);
  f32x4 acc = {0.f, 0.f, 0.f, 0.f};
  acc = __builtin_amdgcn_mfma_f32_16x16x32_bf16(am0, bl0, acc, 0, 0, 0);
  acc = __builtin_amdgcn_mfma_f32_16x16x32_bf16(am1, bl1, acc, 0, 0, 0);
  acc = __builtin_amdgcn_mfma_f32_16x16x32_bf16(ax0, br0, acc, 0, 0, 0);
  acc = __builtin_amdgcn_mfma_f32_16x16x32_bf16(ax1, br1, acc, 0, 0, 0);
#pragma unroll
  for (int r2 = 0; r2 < 4; ++r2) {
    const int node = nodebase + quad * 4 + r2;
    if (node < n_nodes) out[(size_t)node * FDIM + wave * 16 + m] = acc[r2];
  }
}

extern "C" void kernel_launch(void* const* d_in, const int* in_sizes, int n_in,
                              void* d_out, int out_size, void* d_ws, size_t ws_size,
                              hipStream_t stream) {
  const float* x = (const float*)d_in[0];
  const int* edge_index = (const int*)d_in[1];
  const float* Wl = (const float*)d_in[2];
  const float* Wr = (const float*)d_in[3];
  float* out = (float*)d_out;

  const int n_nodes = in_sizes[0] / FDIM;  // 100000
  const int n_edges = in_sizes[1] / 2;     // 1200000
  const int* e_src = edge_index;
  const int* e_dst = edge_index + n_edges;

  const int NBKT = (n_nodes + NPB - 1) / NPB;  // 196

  // ws layout
  int* cursorB = (int*)d_ws;            // MAXBKT
  int* offsets = cursorB + MAXBKT;      // N+1
  int* praw = offsets + n_nodes + 2;
  int2* pairs = (int2*)(((uintptr_t)praw + 15) & ~(uintptr_t)15);  // NBKT*CAP
  int* sorted_src = (int*)(pairs + (size_t)NBKT * CAP);            // E
  ushort* xbuf = (ushort*)(((uintptr_t)(sorted_src + n_edges) + 15) &
                           ~(uintptr_t)15);  // N*64 bf16
  ushort* WlT = xbuf + (size_t)n_nodes * FDIM;  // 4096
  ushort* WrT = WlT + FDIM * FDIM;              // 4096

  const int xquads = n_nodes * (FDIM / 4);  // 1.6M float4 units
  const int XB = (xquads + 255) / 256;      // 6250
  const int EB = (n_edges + PART_T - 1) / PART_T;  // 586

  k_cvt<<<XB + 16, 256, 0, stream>>>(x, Wl, Wr, xbuf, WlT, WrT, cursorB, offsets,
                                     xquads, XB, n_nodes, n_edges);
  k_part<<<EB, 256, 0, stream>>>(e_src, e_dst, cursorB, pairs, n_edges);
  k_sub<<<NBKT, 512, 0, stream>>>(pairs, cursorB, offsets, sorted_src, n_nodes,
                                  NBKT);
  k_fused<<<(n_nodes + 15) / 16, 256, 0, stream>>>(xbuf, offsets, sorted_src, WlT,
                                                   WrT, out, n_nodes);
}